// Round 3
// baseline (1382.314 us; speedup 1.0000x reference)
//
#include <hip/hip_runtime.h>
#include <math.h>

#define CC 64
#define HW 4096
#define NB 4
#define NT 10
#define TR 4                 // tile rows per block
#define LROW 68              // 64 cols + 2 halo + 2 pad
#define LICS 412             // per-ic LDS stride (6*68=408, padded to %4==0 for float4)
#define ICCH 16              // input channels staged per chunk
#define CHUNK_LOGICAL (ICCH*408)

__device__ __forceinline__ float sigm(float x) { return 1.0f / (1.0f + expf(-x)); }

// ---------------------------------------------------------------------------
// Kernel A: rz = conv3x3(prev_y, w_rz) + b_rz (129 ch, padded to 136)
// thread layout: tx(16 cols x4) * t4(4 rows) * ocq(4 wave-uniform), 2 oc/thread.
// ocg 0..7 -> z (oc 0..63); ocg 8..15 -> r (oc 64..127); ocg 16 -> thr (oc 128)
// ---------------------------------------------------------------------------
__global__ __launch_bounds__(256) void convA_kernel(
    const float* __restrict__ prev_y,
    const float* __restrict__ xt_t,
    const float* __restrict__ w_rz,
    const float* __restrict__ b_rz,
    float* __restrict__ ws_u,
    float* __restrict__ ws_ry,
    float* __restrict__ ws_thr,
    int first)
{
    __shared__ float lds[ICCH * LICS];
    const int tx  = threadIdx.x & 15;
    const int t4  = (threadIdx.x >> 4) & 3;
    const int ocq = threadIdx.x >> 6;          // wave index (wave-uniform)
    const int ocg = blockIdx.x;                // 0..16
    const int r0  = blockIdx.y * TR;
    const int b   = blockIdx.z;
    const int oc_base = ocg * 8;

    float acc[2][4];
#pragma unroll
    for (int o = 0; o < 2; ++o)
#pragma unroll
        for (int p = 0; p < 4; ++p) acc[o][p] = 0.f;

    if (!first) {
        const int oc_qs = __builtin_amdgcn_readfirstlane(ocq);  // scalar -> s_load weights
        for (int cg = 0; cg < CC / ICCH; ++cg) {
            __syncthreads();
            const float* src = prev_y + ((size_t)b * CC + cg * ICCH) * HW;
            for (int idx = threadIdx.x; idx < CHUNK_LOGICAL; idx += 256) {
                int ic  = idx / 408;
                int rem = idx - ic * 408;
                int row = rem / 68;
                int col = rem - row * 68;
                int sr = r0 - 1 + row;
                int sc = col - 1;
                float v = 0.f;
                if (sr >= 0 && sr < 64 && sc >= 0 && sc < 64)
                    v = src[ic * HW + sr * 64 + sc];
                lds[ic * LICS + rem] = v;
            }
            __syncthreads();
            for (int ic = 0; ic < ICCH; ++ic) {
                float win[3][8];
#pragma unroll
                for (int dr = 0; dr < 3; ++dr) {
                    const float4* lp = (const float4*)&lds[ic * LICS + (t4 + dr) * 68 + 4 * tx];
                    float4 a = lp[0], c = lp[1];
                    win[dr][0]=a.x; win[dr][1]=a.y; win[dr][2]=a.z; win[dr][3]=a.w;
                    win[dr][4]=c.x; win[dr][5]=c.y; win[dr][6]=c.z; win[dr][7]=c.w;
                }
                const int icg = cg * ICCH + ic;
#pragma unroll
                for (int o = 0; o < 2; ++o) {
                    int ocw = oc_base + oc_qs * 2 + o;
                    if (ocw > 128) ocw = 128;           // pad lanes read valid mem, result unused
                    const float* w9 = w_rz + ((size_t)ocw * CC + icg) * 9;
                    float w0=w9[0],w1=w9[1],w2=w9[2],w3=w9[3],w4=w9[4];
                    float w5=w9[5],w6=w9[6],w7=w9[7],w8=w9[8];
#pragma unroll
                    for (int p = 0; p < 4; ++p) {
                        float s = acc[o][p];
                        s = fmaf(w0, win[0][p],   s);
                        s = fmaf(w1, win[0][p+1], s);
                        s = fmaf(w2, win[0][p+2], s);
                        s = fmaf(w3, win[1][p],   s);
                        s = fmaf(w4, win[1][p+1], s);
                        s = fmaf(w5, win[1][p+2], s);
                        s = fmaf(w6, win[2][p],   s);
                        s = fmaf(w7, win[2][p+1], s);
                        s = fmaf(w8, win[2][p+2], s);
                        acc[o][p] = s;
                    }
                }
            }
        }
    }

    const int gr = r0 + t4;
    const size_t pix = (size_t)gr * 64 + 4 * tx;

    if (ocg < 8) {                       // z-type: update gate
#pragma unroll
        for (int o = 0; o < 2; ++o) {
            int oc = oc_base + ocq * 2 + o;
            float bias = b_rz[oc];
            const float4 x4 = *(const float4*)(xt_t + ((size_t)b * 192 + oc) * HW + pix);
            float4 outv;
            outv.x = sigm(acc[o][0] + bias + x4.x);
            outv.y = sigm(acc[o][1] + bias + x4.y);
            outv.z = sigm(acc[o][2] + bias + x4.z);
            outv.w = sigm(acc[o][3] + bias + x4.w);
            *(float4*)(ws_u + ((size_t)b * CC + oc) * HW + pix) = outv;
        }
    } else if (ocg < 16) {               // r-type: ry = prev_y * reset_gate
#pragma unroll
        for (int o = 0; o < 2; ++o) {
            int oc = oc_base + ocq * 2 + o;
            int c  = oc - CC;
            float bias = b_rz[oc];
            const float4 x4 = *(const float4*)(xt_t + ((size_t)b * 192 + oc) * HW + pix);
            float4 py;
            if (first) { py = make_float4(0.f, 0.f, 0.f, 0.f); }
            else       { py = *(const float4*)(prev_y + ((size_t)b * CC + c) * HW + pix); }
            float4 outv;
            outv.x = py.x * sigm(acc[o][0] + bias + x4.x);
            outv.y = py.y * sigm(acc[o][1] + bias + x4.y);
            outv.z = py.z * sigm(acc[o][2] + bias + x4.z);
            outv.w = py.w * sigm(acc[o][3] + bias + x4.w);
            *(float4*)(ws_ry + ((size_t)b * CC + c) * HW + pix) = outv;
        }
    } else {                             // thr channel (oc 128): only ocq==0, o==0 real
        if (ocq == 0) {
            float bias = b_rz[2 * CC];
            float4 outv;
            outv.x = sigm(acc[0][0] + bias);
            outv.y = sigm(acc[0][1] + bias);
            outv.z = sigm(acc[0][2] + bias);
            outv.w = sigm(acc[0][3] + bias);
            *(float4*)(ws_thr + (size_t)b * HW + pix) = outv;
        }
    }
}

// ---------------------------------------------------------------------------
// Kernel B-conv: partial f = conv3x3(ry, w_f) over an ic half (split-K 2-way).
// 8 oc per block (2/thread). Partials land in the es[t]/nds[t] output slabs.
// ---------------------------------------------------------------------------
__global__ __launch_bounds__(256) void convB_kernel(
    const float* __restrict__ ry,
    const float* __restrict__ w_f,
    float* __restrict__ part0,
    float* __restrict__ part1)
{
    __shared__ float lds[ICCH * LICS];
    const int tx  = threadIdx.x & 15;
    const int t4  = (threadIdx.x >> 4) & 3;
    const int ocq = threadIdx.x >> 6;
    const int ocg = blockIdx.x & 7;            // 0..7
    const int ks  = blockIdx.x >> 3;           // 0..1 ic half
    const int r0  = blockIdx.y * TR;
    const int b   = blockIdx.z;
    const int oc_base = ocg * 8;

    float acc[2][4];
#pragma unroll
    for (int o = 0; o < 2; ++o)
#pragma unroll
        for (int p = 0; p < 4; ++p) acc[o][p] = 0.f;

    const int oc_qs = __builtin_amdgcn_readfirstlane(ocq);
    for (int cg = 0; cg < 2; ++cg) {           // 2 chunks of 16 ic = this half
        __syncthreads();
        const int icbase = ks * 32 + cg * ICCH;
        const float* src = ry + ((size_t)b * CC + icbase) * HW;
        for (int idx = threadIdx.x; idx < CHUNK_LOGICAL; idx += 256) {
            int ic  = idx / 408;
            int rem = idx - ic * 408;
            int row = rem / 68;
            int col = rem - row * 68;
            int sr = r0 - 1 + row;
            int sc = col - 1;
            float v = 0.f;
            if (sr >= 0 && sr < 64 && sc >= 0 && sc < 64)
                v = src[ic * HW + sr * 64 + sc];
            lds[ic * LICS + rem] = v;
        }
        __syncthreads();
        for (int ic = 0; ic < ICCH; ++ic) {
            float win[3][8];
#pragma unroll
            for (int dr = 0; dr < 3; ++dr) {
                const float4* lp = (const float4*)&lds[ic * LICS + (t4 + dr) * 68 + 4 * tx];
                float4 a = lp[0], c = lp[1];
                win[dr][0]=a.x; win[dr][1]=a.y; win[dr][2]=a.z; win[dr][3]=a.w;
                win[dr][4]=c.x; win[dr][5]=c.y; win[dr][6]=c.z; win[dr][7]=c.w;
            }
            const int icg = icbase + ic;
#pragma unroll
            for (int o = 0; o < 2; ++o) {
                int oc = oc_base + oc_qs * 2 + o;
                const float* w9 = w_f + ((size_t)oc * CC + icg) * 9;
                float w0=w9[0],w1=w9[1],w2=w9[2],w3=w9[3],w4=w9[4];
                float w5=w9[5],w6=w9[6],w7=w9[7],w8=w9[8];
#pragma unroll
                for (int p = 0; p < 4; ++p) {
                    float s = acc[o][p];
                    s = fmaf(w0, win[0][p],   s);
                    s = fmaf(w1, win[0][p+1], s);
                    s = fmaf(w2, win[0][p+2], s);
                    s = fmaf(w3, win[1][p],   s);
                    s = fmaf(w4, win[1][p+1], s);
                    s = fmaf(w5, win[1][p+2], s);
                    s = fmaf(w6, win[2][p],   s);
                    s = fmaf(w7, win[2][p+1], s);
                    s = fmaf(w8, win[2][p+2], s);
                    acc[o][p] = s;
                }
            }
        }
    }

    const int gr = r0 + t4;
    const size_t pix = (size_t)gr * 64 + 4 * tx;
    float* part = ks ? part1 : part0;
#pragma unroll
    for (int o = 0; o < 2; ++o) {
        int oc = oc_base + ocq * 2 + o;
        *(float4*)(part + ((size_t)b * CC + oc) * HW + pix) =
            make_float4(acc[o][0], acc[o][1], acc[o][2], acc[o][3]);
    }
}

// ---------------------------------------------------------------------------
// Kernel B-epi: f = part0+part1+b_f+xi_f ; GRU update + spike epilogue.
// Reads partials from es[t]/nds[t], overwrites them with final e / neg_dist.
// ---------------------------------------------------------------------------
__global__ __launch_bounds__(256) void convB_epi(
    const float* __restrict__ xt_t,
    const float* __restrict__ b_f,
    const float* __restrict__ ws_u,
    const float* __restrict__ ws_thr,
    float* __restrict__ ws_h,
    float* __restrict__ out_y,
    float* __restrict__ out_e,
    float* __restrict__ out_nd,
    int first)
{
    const int i = blockIdx.x * 256 + threadIdx.x;   // one float4 per thread
    const int b   = i >> 16;                        // 65536 quads per batch
    const int rem = i & 65535;
    const int c   = rem >> 10;
    const int p4  = rem & 1023;
    const size_t off = ((size_t)(b * CC + c)) * HW + 4 * p4;
    const size_t pix = (size_t)4 * p4;

    const float4 f0 = *(const float4*)(out_e + off);
    const float4 f1 = *(const float4*)(out_nd + off);
    const float4 x4 = *(const float4*)(xt_t + ((size_t)b * 192 + 2 * CC + c) * HW + 4 * p4);
    const float4 u4 = *(const float4*)(ws_u + off);
    const float4 t4 = *(const float4*)(ws_thr + (size_t)b * HW + pix);
    float bias = b_f[c];
    float4 h4;
    if (first) { h4 = make_float4(0.f, 0.f, 0.f, 0.f); }
    else       { h4 = *(const float4*)(ws_h + off); }

    float fx[4] = { f0.x + f1.x + bias + x4.x, f0.y + f1.y + bias + x4.y,
                    f0.z + f1.z + bias + x4.z, f0.w + f1.w + bias + x4.w };
    float uu[4] = { u4.x, u4.y, u4.z, u4.w };
    float hh[4] = { h4.x, h4.y, h4.z, h4.w };
    float tt[4] = { t4.x, t4.y, t4.z, t4.w };
    float yv[4], ev[4], nd[4], hc[4];
#pragma unroll
    for (int j = 0; j < 4; ++j) {
        float ig = tanhf(fx[j]);
        float hn = (1.f - uu[j]) * hh[j] + uu[j] * ig;
        float d  = hn - tt[j];
        bool pos = d > 0.f;
        ev[j] = pos ? 1.f : 0.f;
        yv[j] = pos ? hn : 0.f;
        nd[j] = (d < 0.f) ? (tt[j] - hn) : 0.f;
        hc[j] = pos ? (hn - tt[j]) : hn;
    }
    *(float4*)(out_y + off)  = make_float4(yv[0], yv[1], yv[2], yv[3]);
    *(float4*)(out_e + off)  = make_float4(ev[0], ev[1], ev[2], ev[3]);
    *(float4*)(out_nd + off) = make_float4(nd[0], nd[1], nd[2], nd[3]);
    *(float4*)(ws_h + off)   = make_float4(hc[0], hc[1], hc[2], hc[3]);
}

extern "C" void kernel_launch(void* const* d_in, const int* in_sizes, int n_in,
                              void* d_out, int out_size, void* d_ws, size_t ws_size,
                              hipStream_t stream) {
    const float* xt   = (const float*)d_in[0];
    const float* w_rz = (const float*)d_in[1];
    const float* b_rz = (const float*)d_in[2];
    const float* w_f  = (const float*)d_in[3];
    const float* b_f  = (const float*)d_in[4];
    float* out = (float*)d_out;
    float* ws  = (float*)d_ws;

    const size_t NCHW = (size_t)NB * CC * HW;   // 1,048,576 floats
    float* ws_u   = ws;
    float* ws_ry  = ws + NCHW;
    float* ws_thr = ws + 2 * NCHW;
    float* ws_h   = ws + 2 * NCHW + (size_t)NB * HW;

    float* ys  = out;
    float* es  = out + (size_t)NT * NCHW;
    float* nds = out + 2 * (size_t)NT * NCHW;

    for (int t = 0; t < NT; ++t) {
        const float* xtt = xt + (size_t)t * NB * 192 * HW;
        const float* py  = (t == 0) ? xtt : (ys + (size_t)(t - 1) * NCHW);
        hipLaunchKernelGGL(convA_kernel, dim3(17, 16, 4), dim3(256), 0, stream,
                           py, xtt, w_rz, b_rz, ws_u, ws_ry, ws_thr, (t == 0) ? 1 : 0);
        hipLaunchKernelGGL(convB_kernel, dim3(16, 16, 4), dim3(256), 0, stream,
                           ws_ry, w_f, es + (size_t)t * NCHW, nds + (size_t)t * NCHW);
        hipLaunchKernelGGL(convB_epi, dim3(1024), dim3(256), 0, stream,
                           xtt, b_f, ws_u, ws_thr, ws_h,
                           ys + (size_t)t * NCHW, es + (size_t)t * NCHW,
                           nds + (size_t)t * NCHW, (t == 0) ? 1 : 0);
    }
}

// Round 4
// 1226.309 us; speedup vs baseline: 1.1272x; 1.1272x over previous
//
#include <hip/hip_runtime.h>
#include <math.h>

#define CC 64
#define HW 4096
#define NB 4
#define NT 10
#define TR 4                    // output rows per block
#define ICCH 16                 // input channels staged per chunk
#define ICSTRIDE 408            // floats per ic in LDS (6 rows * 68)
#define BUFSZ (ICCH*ICSTRIDE)   // 6528 floats per split-K half

__device__ __forceinline__ float sigm(float x) { return 1.0f / (1.0f + expf(-x)); }

// Stage 16 input channels (rows r0-1 .. r0+4, halo-shifted: lds col j = image col j-1)
// lane 0..255 -> (ic = lane>>4, quad q = lane&15). Row validity is block-uniform.
__device__ __forceinline__ void stage16(float* __restrict__ buf,
                                        const float* __restrict__ src,   // [16][HW]
                                        int r0, int lane)
{
    const int ic = lane >> 4;
    const int q  = lane & 15;
    float* dst = buf + ic * ICSTRIDE + 4 * q;
    const float* g = src + ic * HW;
#pragma unroll
    for (int row = 0; row < 6; ++row) {
        int sr = r0 - 1 + row;
        float4 v = make_float4(0.f, 0.f, 0.f, 0.f);
        float tail = 0.f;
        if (sr >= 0 && sr < 64) {                      // uniform scalar branch
            const float* grow = g + sr * 64;
            float4 bq = *(const float4*)(grow + 4 * q);          // image 4q..4q+3 (aligned)
            float aw  = (q == 0) ? 0.f : grow[4 * q - 1];        // image 4q-1
            v = make_float4(aw, bq.x, bq.y, bq.z);
            tail = bq.w;                                         // image 4q+3 (q=15: col 63)
        }
        *(float4*)(dst + row * 68) = v;
        if (q == 15)   // lds cols 64..67 = image 63..66 -> (img63, 0, 0, 0)
            *(float4*)(buf + ic * ICSTRIDE + row * 68 + 64) = make_float4(tail, 0.f, 0.f, 0.f);
    }
}

// ---------------------------------------------------------------------------
// Kernel A: rz = conv3x3(prev_y, w_rz) + b_rz (129 ch, padded to 136)
// 512 threads: tx16(4col) x t4(4row) x ocq4(2oc) x ks2(in-block split-K over ic).
// ocg 0..7 -> z; 8..15 -> r; 16 -> thr.
// ---------------------------------------------------------------------------
__global__ __launch_bounds__(512, 6) void convA_kernel(
    const float* __restrict__ prev_y,
    const float* __restrict__ xt_t,
    const float* __restrict__ w_rz,
    const float* __restrict__ b_rz,
    float* __restrict__ ws_u,
    float* __restrict__ ws_ry,
    float* __restrict__ ws_thr,
    int first)
{
    __shared__ float lds[2 * BUFSZ];
    const int tid  = threadIdx.x;
    const int tx   = tid & 15;
    const int t4   = (tid >> 4) & 3;
    const int ocq  = (tid >> 6) & 3;
    const int ks   = tid >> 8;
    const int lane = tid & 255;
    const int ocg  = blockIdx.x;           // 0..16
    const int r0   = blockIdx.y * TR;
    const int b    = blockIdx.z;
    const int oc_base = ocg * 8;

    float acc[2][4];
#pragma unroll
    for (int o = 0; o < 2; ++o)
#pragma unroll
        for (int p = 0; p < 4; ++p) acc[o][p] = 0.f;

    if (!first) {
        const int oc0 = __builtin_amdgcn_readfirstlane(oc_base + ocq * 2);
        float* buf = lds + ks * BUFSZ;
        for (int cg = 0; cg < 2; ++cg) {
            __syncthreads();
            stage16(buf, prev_y + ((size_t)b * CC + ks * 32 + cg * ICCH) * HW, r0, lane);
            __syncthreads();
            for (int ic = 0; ic < ICCH; ++ic) {
                const float* p = buf + ic * ICSTRIDE + t4 * 68 + 4 * tx;
                float win[3][6];
#pragma unroll
                for (int dr = 0; dr < 3; ++dr) {
                    float4 a = *(const float4*)(p + dr * 68);
                    float2 c = *(const float2*)(p + dr * 68 + 4);
                    win[dr][0] = a.x; win[dr][1] = a.y; win[dr][2] = a.z;
                    win[dr][3] = a.w; win[dr][4] = c.x; win[dr][5] = c.y;
                }
                const int icg = ks * 32 + cg * ICCH + ic;
#pragma unroll
                for (int o = 0; o < 2; ++o) {
                    int ocw = oc0 + o;
                    if (ocw > 128) ocw = 128;      // pad lanes read valid mem, result unused
                    const float* w9 = w_rz + ((size_t)ocw * CC + icg) * 9;
                    float w0=w9[0],w1=w9[1],w2=w9[2],w3=w9[3],w4=w9[4];
                    float w5=w9[5],w6=w9[6],w7=w9[7],w8=w9[8];
#pragma unroll
                    for (int pp = 0; pp < 4; ++pp) {
                        float s = acc[o][pp];
                        s = fmaf(w0, win[0][pp],   s);
                        s = fmaf(w1, win[0][pp+1], s);
                        s = fmaf(w2, win[0][pp+2], s);
                        s = fmaf(w3, win[1][pp],   s);
                        s = fmaf(w4, win[1][pp+1], s);
                        s = fmaf(w5, win[1][pp+2], s);
                        s = fmaf(w6, win[2][pp],   s);
                        s = fmaf(w7, win[2][pp+1], s);
                        s = fmaf(w8, win[2][pp+2], s);
                        acc[o][pp] = s;
                    }
                }
            }
        }
    }

    // in-block split-K combine: ks1 -> LDS, ks0 adds + epilogue
    __syncthreads();
    if (ks == 1) {
        *(float4*)(lds + lane * 4)        = make_float4(acc[0][0], acc[0][1], acc[0][2], acc[0][3]);
        *(float4*)(lds + 1024 + lane * 4) = make_float4(acc[1][0], acc[1][1], acc[1][2], acc[1][3]);
    }
    __syncthreads();
    if (ks == 0) {
        float4 p0 = *(const float4*)(lds + lane * 4);
        float4 p1 = *(const float4*)(lds + 1024 + lane * 4);
        acc[0][0] += p0.x; acc[0][1] += p0.y; acc[0][2] += p0.z; acc[0][3] += p0.w;
        acc[1][0] += p1.x; acc[1][1] += p1.y; acc[1][2] += p1.z; acc[1][3] += p1.w;

        const int gr = r0 + t4;
        const size_t pix = (size_t)gr * 64 + 4 * tx;

        if (ocg < 8) {                       // z: update gate
#pragma unroll
            for (int o = 0; o < 2; ++o) {
                int oc = oc_base + ocq * 2 + o;
                float bias = b_rz[oc];
                const float4 x4 = *(const float4*)(xt_t + ((size_t)b * 192 + oc) * HW + pix);
                float4 outv;
                outv.x = sigm(acc[o][0] + bias + x4.x);
                outv.y = sigm(acc[o][1] + bias + x4.y);
                outv.z = sigm(acc[o][2] + bias + x4.z);
                outv.w = sigm(acc[o][3] + bias + x4.w);
                *(float4*)(ws_u + ((size_t)b * CC + oc) * HW + pix) = outv;
            }
        } else if (ocg < 16) {               // r: ry = prev_y * reset_gate
#pragma unroll
            for (int o = 0; o < 2; ++o) {
                int oc = oc_base + ocq * 2 + o;
                int c  = oc - CC;
                float bias = b_rz[oc];
                const float4 x4 = *(const float4*)(xt_t + ((size_t)b * 192 + oc) * HW + pix);
                float4 py;
                if (first) { py = make_float4(0.f, 0.f, 0.f, 0.f); }
                else       { py = *(const float4*)(prev_y + ((size_t)b * CC + c) * HW + pix); }
                float4 outv;
                outv.x = py.x * sigm(acc[o][0] + bias + x4.x);
                outv.y = py.y * sigm(acc[o][1] + bias + x4.y);
                outv.z = py.z * sigm(acc[o][2] + bias + x4.z);
                outv.w = py.w * sigm(acc[o][3] + bias + x4.w);
                *(float4*)(ws_ry + ((size_t)b * CC + c) * HW + pix) = outv;
            }
        } else {                             // thr (oc 128): ocq==0, o==0 real
            if (ocq == 0) {
                float bias = b_rz[2 * CC];
                float4 outv;
                outv.x = sigm(acc[0][0] + bias);
                outv.y = sigm(acc[0][1] + bias);
                outv.z = sigm(acc[0][2] + bias);
                outv.w = sigm(acc[0][3] + bias);
                *(float4*)(ws_thr + (size_t)b * HW + pix) = outv;
            }
        }
    }
}

// ---------------------------------------------------------------------------
// Kernel B: f = conv3x3(ry, w_f) + b_f + xi_f ; fused GRU update + spike.
// Same structure: 512 threads, in-block split-K, 8 oc per block.
// ---------------------------------------------------------------------------
__global__ __launch_bounds__(512, 6) void convB_kernel(
    const float* __restrict__ ry,
    const float* __restrict__ xt_t,
    const float* __restrict__ w_f,
    const float* __restrict__ b_f,
    const float* __restrict__ ws_u,
    const float* __restrict__ ws_thr,
    float* __restrict__ ws_h,
    float* __restrict__ out_y,
    float* __restrict__ out_e,
    float* __restrict__ out_nd,
    int first)
{
    __shared__ float lds[2 * BUFSZ];
    const int tid  = threadIdx.x;
    const int tx   = tid & 15;
    const int t4   = (tid >> 4) & 3;
    const int ocq  = (tid >> 6) & 3;
    const int ks   = tid >> 8;
    const int lane = tid & 255;
    const int ocg  = blockIdx.x;           // 0..7
    const int r0   = blockIdx.y * TR;
    const int b    = blockIdx.z;
    const int oc_base = ocg * 8;

    float acc[2][4];
#pragma unroll
    for (int o = 0; o < 2; ++o)
#pragma unroll
        for (int p = 0; p < 4; ++p) acc[o][p] = 0.f;

    {
        const int oc0 = __builtin_amdgcn_readfirstlane(oc_base + ocq * 2);
        float* buf = lds + ks * BUFSZ;
        for (int cg = 0; cg < 2; ++cg) {
            __syncthreads();
            stage16(buf, ry + ((size_t)b * CC + ks * 32 + cg * ICCH) * HW, r0, lane);
            __syncthreads();
            for (int ic = 0; ic < ICCH; ++ic) {
                const float* p = buf + ic * ICSTRIDE + t4 * 68 + 4 * tx;
                float win[3][6];
#pragma unroll
                for (int dr = 0; dr < 3; ++dr) {
                    float4 a = *(const float4*)(p + dr * 68);
                    float2 c = *(const float2*)(p + dr * 68 + 4);
                    win[dr][0] = a.x; win[dr][1] = a.y; win[dr][2] = a.z;
                    win[dr][3] = a.w; win[dr][4] = c.x; win[dr][5] = c.y;
                }
                const int icg = ks * 32 + cg * ICCH + ic;
#pragma unroll
                for (int o = 0; o < 2; ++o) {
                    const float* w9 = w_f + ((size_t)(oc0 + o) * CC + icg) * 9;
                    float w0=w9[0],w1=w9[1],w2=w9[2],w3=w9[3],w4=w9[4];
                    float w5=w9[5],w6=w9[6],w7=w9[7],w8=w9[8];
#pragma unroll
                    for (int pp = 0; pp < 4; ++pp) {
                        float s = acc[o][pp];
                        s = fmaf(w0, win[0][pp],   s);
                        s = fmaf(w1, win[0][pp+1], s);
                        s = fmaf(w2, win[0][pp+2], s);
                        s = fmaf(w3, win[1][pp],   s);
                        s = fmaf(w4, win[1][pp+1], s);
                        s = fmaf(w5, win[1][pp+2], s);
                        s = fmaf(w6, win[2][pp],   s);
                        s = fmaf(w7, win[2][pp+1], s);
                        s = fmaf(w8, win[2][pp+2], s);
                        acc[o][pp] = s;
                    }
                }
            }
        }
    }

    __syncthreads();
    if (ks == 1) {
        *(float4*)(lds + lane * 4)        = make_float4(acc[0][0], acc[0][1], acc[0][2], acc[0][3]);
        *(float4*)(lds + 1024 + lane * 4) = make_float4(acc[1][0], acc[1][1], acc[1][2], acc[1][3]);
    }
    __syncthreads();
    if (ks == 0) {
        float4 p0 = *(const float4*)(lds + lane * 4);
        float4 p1 = *(const float4*)(lds + 1024 + lane * 4);
        acc[0][0] += p0.x; acc[0][1] += p0.y; acc[0][2] += p0.z; acc[0][3] += p0.w;
        acc[1][0] += p1.x; acc[1][1] += p1.y; acc[1][2] += p1.z; acc[1][3] += p1.w;

        const int gr = r0 + t4;
        const size_t pix = (size_t)gr * 64 + 4 * tx;
        const float4 t4q = *(const float4*)(ws_thr + (size_t)b * HW + pix);
#pragma unroll
        for (int o = 0; o < 2; ++o) {
            int oc = oc_base + ocq * 2 + o;
            float bias = b_f[oc];
            const size_t coff = ((size_t)b * CC + oc) * HW + pix;
            const float4 x4 = *(const float4*)(xt_t + ((size_t)b * 192 + 2 * CC + oc) * HW + pix);
            const float4 u4 = *(const float4*)(ws_u + coff);
            float4 h4;
            if (first) { h4 = make_float4(0.f, 0.f, 0.f, 0.f); }
            else       { h4 = *(const float4*)(ws_h + coff); }

            float fx[4] = { acc[o][0] + bias + x4.x, acc[o][1] + bias + x4.y,
                            acc[o][2] + bias + x4.z, acc[o][3] + bias + x4.w };
            float uu[4] = { u4.x, u4.y, u4.z, u4.w };
            float hh[4] = { h4.x, h4.y, h4.z, h4.w };
            float tt[4] = { t4q.x, t4q.y, t4q.z, t4q.w };
            float yv[4], ev[4], nd[4], hc[4];
#pragma unroll
            for (int j = 0; j < 4; ++j) {
                float ig = tanhf(fx[j]);
                float hn = (1.f - uu[j]) * hh[j] + uu[j] * ig;
                float d  = hn - tt[j];
                bool pos = d > 0.f;
                ev[j] = pos ? 1.f : 0.f;
                yv[j] = pos ? hn : 0.f;
                nd[j] = (d < 0.f) ? (tt[j] - hn) : 0.f;
                hc[j] = pos ? (hn - tt[j]) : hn;
            }
            *(float4*)(out_y + coff)  = make_float4(yv[0], yv[1], yv[2], yv[3]);
            *(float4*)(out_e + coff)  = make_float4(ev[0], ev[1], ev[2], ev[3]);
            *(float4*)(out_nd + coff) = make_float4(nd[0], nd[1], nd[2], nd[3]);
            *(float4*)(ws_h + coff)   = make_float4(hc[0], hc[1], hc[2], hc[3]);
        }
    }
}

extern "C" void kernel_launch(void* const* d_in, const int* in_sizes, int n_in,
                              void* d_out, int out_size, void* d_ws, size_t ws_size,
                              hipStream_t stream) {
    const float* xt   = (const float*)d_in[0];
    const float* w_rz = (const float*)d_in[1];
    const float* b_rz = (const float*)d_in[2];
    const float* w_f  = (const float*)d_in[3];
    const float* b_f  = (const float*)d_in[4];
    float* out = (float*)d_out;
    float* ws  = (float*)d_ws;

    const size_t NCHW = (size_t)NB * CC * HW;   // 1,048,576 floats
    float* ws_u   = ws;
    float* ws_ry  = ws + NCHW;
    float* ws_thr = ws + 2 * NCHW;
    float* ws_h   = ws + 2 * NCHW + (size_t)NB * HW;

    float* ys  = out;
    float* es  = out + (size_t)NT * NCHW;
    float* nds = out + 2 * (size_t)NT * NCHW;

    for (int t = 0; t < NT; ++t) {
        const float* xtt = xt + (size_t)t * NB * 192 * HW;
        const float* py  = (t == 0) ? xtt : (ys + (size_t)(t - 1) * NCHW);
        hipLaunchKernelGGL(convA_kernel, dim3(17, 16, 4), dim3(512), 0, stream,
                           py, xtt, w_rz, b_rz, ws_u, ws_ry, ws_thr, (t == 0) ? 1 : 0);
        hipLaunchKernelGGL(convB_kernel, dim3(8, 16, 4), dim3(512), 0, stream,
                           ws_ry, xtt, w_f, b_f, ws_u, ws_thr, ws_h,
                           ys + (size_t)t * NCHW, es + (size_t)t * NCHW,
                           nds + (size_t)t * NCHW, (t == 0) ? 1 : 0);
    }
}